// Round 1
// baseline (135.195 us; speedup 1.0000x reference)
//
#include <hip/hip_runtime.h>

typedef __bf16 bf16_t;
typedef __bf16 bf16x4 __attribute__((ext_vector_type(4)));
typedef __bf16 bf16x8 __attribute__((ext_vector_type(8)));
typedef float  f32x4  __attribute__((ext_vector_type(4)));

#define B_SZ  16
#define L_SEQ 2048
#define D_H   64
#define QB    64
#define KB    32
#define NQT   (L_SEQ / QB)   // 32

// softmax is over (S/8); fold log2(e)/8 into Q so MFMA output is in log2 units
#define QSCALE 0.18033688011112043f

__global__ __launch_bounds__(256, 2)
void attn_fwd_kernel(const float* __restrict__ Qg, const float* __restrict__ Kg,
                     const float* __restrict__ Vg, float* __restrict__ Og)
{
    const int qt   = (NQT - 1) - blockIdx.x;   // big causal tiles first
    const int b    = blockIdx.y;
    const int tid  = threadIdx.x;
    const int wave = tid >> 6;
    const int lane = tid & 63;
    const int lg   = lane >> 4;    // lane group 0..3
    const int lc   = lane & 15;

    __shared__ __align__(16) bf16_t K_lds[KB][72];      // 64 + 8 pad (16B-aligned rows)
    __shared__ __align__(16) bf16_t Vt_lds[D_H][40];    // transposed V: [d][k], 32 + 8 pad
    __shared__ __align__(16) bf16_t P_lds[4][16][40];   // per-wave P tile

    const size_t bbase = (size_t)b * L_SEQ * D_H;

    // ---- Q fragments in registers, pre-scaled ----
    const int qrow = qt * QB + wave * 16 + lc;
    bf16x8 qa[2];
#pragma unroll
    for (int h = 0; h < 2; ++h) {
        const float* qp = Qg + bbase + (size_t)qrow * D_H + h * 32 + lg * 8;
        const f32x4 f0 = *reinterpret_cast<const f32x4*>(qp);
        const f32x4 f1 = *reinterpret_cast<const f32x4*>(qp + 4);
        bf16x8 a;
#pragma unroll
        for (int j = 0; j < 4; ++j) { a[j] = (bf16_t)(f0[j] * QSCALE); a[4 + j] = (bf16_t)(f1[j] * QSCALE); }
        qa[h] = a;
    }

    f32x4 o[4];
    float m[4], l[4];
#pragma unroll
    for (int r = 0; r < 4; ++r) { o[r] = (f32x4){0.f, 0.f, 0.f, 0.f}; m[r] = -1e30f; l[r] = 0.f; }

    const int qg0 = qt * QB + wave * 16 + lg * 4;   // global q row of acc reg 0
    const int nkt = 2 * qt + 2;                     // causal: only tiles with k <= q-tile end

    for (int kt = 0; kt < nkt; ++kt) {
        const int kbase = kt * KB;
        __syncthreads();   // previous tile fully consumed before overwrite
        if (tid < 128) {
            // stage K tile (32x64 fp32 -> bf16, row-major)
#pragma unroll
            for (int i = 0; i < 4; ++i) {
                const int f  = i * 128 + tid;        // float4 index 0..511
                const int r  = f >> 4;
                const int c4 = (f & 15) * 4;
                const f32x4 kv = *reinterpret_cast<const f32x4*>(Kg + bbase + (size_t)(kbase + r) * D_H + c4);
                bf16x4 k4 = { (bf16_t)kv[0], (bf16_t)kv[1], (bf16_t)kv[2], (bf16_t)kv[3] };
                *reinterpret_cast<bf16x4*>(&K_lds[r][c4]) = k4;
            }
        } else {
            // stage V tile transposed: per-thread 4x4 block
            const int u  = tid - 128;
            const int bi = u >> 4;                   // k-block 0..7
            const int bj = u & 15;                   // d-block 0..15
            f32x4 rows[4];
#pragma unroll
            for (int i = 0; i < 4; ++i)
                rows[i] = *reinterpret_cast<const f32x4*>(Vg + bbase + (size_t)(kbase + bi * 4 + i) * D_H + bj * 4);
#pragma unroll
            for (int j = 0; j < 4; ++j) {
                bf16x4 cj = { (bf16_t)rows[0][j], (bf16_t)rows[1][j], (bf16_t)rows[2][j], (bf16_t)rows[3][j] };
                *reinterpret_cast<bf16x4*>(&Vt_lds[bj * 4 + j][bi * 4]) = cj;
            }
        }
        __syncthreads();

        // ---- S = Q K^T (log2 units). Same (lane,j)->d map for both operands. ----
        f32x4 s[2];
#pragma unroll
        for (int n = 0; n < 2; ++n) {
            f32x4 acc = (f32x4){0.f, 0.f, 0.f, 0.f};
#pragma unroll
            for (int h = 0; h < 2; ++h) {
                const bf16x8 kb = *reinterpret_cast<const bf16x8*>(&K_lds[n * 16 + lc][h * 32 + lg * 8]);
                acc = __builtin_amdgcn_mfma_f32_16x16x32_bf16(qa[h], kb, acc, 0, 0, 0);
            }
            s[n] = acc;
        }

        // ---- causal mask: k > q -> -inf ----
#pragma unroll
        for (int n = 0; n < 2; ++n) {
            const int kg = kbase + n * 16 + lc;
#pragma unroll
            for (int r = 0; r < 4; ++r)
                if (kg > qg0 + r) s[n][r] = -1e30f;
        }

        // ---- online softmax (base-2). Acc row r lives in lanes sharing lg; reduce over lc. ----
        float alpha[4];
#pragma unroll
        for (int r = 0; r < 4; ++r) {
            float mx = fmaxf(s[0][r], s[1][r]);
            mx = fmaxf(mx, __shfl_xor(mx, 1));
            mx = fmaxf(mx, __shfl_xor(mx, 2));
            mx = fmaxf(mx, __shfl_xor(mx, 4));
            mx = fmaxf(mx, __shfl_xor(mx, 8));
            const float mn = fmaxf(m[r], mx);
            alpha[r] = exp2f(m[r] - mn);
            m[r] = mn;
            const float p0 = exp2f(s[0][r] - mn);
            const float p1 = exp2f(s[1][r] - mn);
            // round P to bf16 NOW; denominator uses the rounded values so l matches PV exactly
            const bf16_t b0 = (bf16_t)p0, b1 = (bf16_t)p1;
            P_lds[wave][lg * 4 + r][lc]      = b0;
            P_lds[wave][lg * 4 + r][16 + lc] = b1;
            float rs = (float)b0 + (float)b1;
            rs += __shfl_xor(rs, 1);
            rs += __shfl_xor(rs, 2);
            rs += __shfl_xor(rs, 4);
            rs += __shfl_xor(rs, 8);
            l[r] = l[r] * alpha[r] + rs;
        }
#pragma unroll
        for (int dt = 0; dt < 4; ++dt) {
#pragma unroll
            for (int r = 0; r < 4; ++r) o[dt][r] *= alpha[r];
        }
        __syncthreads();   // P visible (uniform barrier count across waves)

        // ---- O += P V. Same (lane,j)->k map for P (A) and Vt (B). ----
        const bf16x8 pa = *reinterpret_cast<const bf16x8*>(&P_lds[wave][lc][lg * 8]);
#pragma unroll
        for (int dt = 0; dt < 4; ++dt) {
            const bf16x8 vb = *reinterpret_cast<const bf16x8*>(&Vt_lds[dt * 16 + lc][lg * 8]);
            o[dt] = __builtin_amdgcn_mfma_f32_16x16x32_bf16(pa, vb, o[dt], 0, 0, 0);
        }
    }

    // ---- epilogue: O / l ----
#pragma unroll
    for (int r = 0; r < 4; ++r) {
        const float inv = 1.0f / l[r];
        float* op = Og + bbase + (size_t)(qg0 + r) * D_H + lc;
#pragma unroll
        for (int dt = 0; dt < 4; ++dt) op[dt * 16] = o[dt][r] * inv;
    }
}

extern "C" void kernel_launch(void* const* d_in, const int* in_sizes, int n_in,
                              void* d_out, int out_size, void* d_ws, size_t ws_size,
                              hipStream_t stream)
{
    const float* Q = (const float*)d_in[0];
    const float* K = (const float*)d_in[1];
    const float* V = (const float*)d_in[2];
    float* O = (float*)d_out;
    dim3 grid(NQT, B_SZ);
    attn_fwd_kernel<<<grid, 256, 0, stream>>>(Q, K, V, O);
}

// Round 2
// 62.394 us; speedup vs baseline: 2.1668x; 2.1668x over previous
//
#include <hip/hip_runtime.h>

typedef __bf16 bf16_t;
typedef __bf16 bf16x4 __attribute__((ext_vector_type(4)));
typedef __bf16 bf16x8 __attribute__((ext_vector_type(8)));
typedef float  f32x4  __attribute__((ext_vector_type(4)));

#define B_SZ  16
#define L_SEQ 2048
#define D_H   64
#define QB    64
#define KB    64
#define NQT   (L_SEQ / QB)   // 32
#define KPAD  72

// softmax is over (S/8); fold log2(e)/8 into Q so MFMA output is in log2 units
#define QSCALE 0.18033688011112043f

__global__ __launch_bounds__(256)
void attn_fwd_kernel(const float* __restrict__ Qg, const float* __restrict__ Kg,
                     const float* __restrict__ Vg, float* __restrict__ Og)
{
    // ---- XCD-aware decode: 2 batches per XCD (K+V = 2 MB -> fits 4 MB L2),
    //      balanced qt pairing: CU c runs qt=31-c then qt=c (33 iters each). ----
    const int lin  = blockIdx.x;          // 0..511
    const int xcd  = lin & 7;
    const int slot = lin >> 3;            // 0..63
    const int half = slot >> 5;           // 0/1 -> which of the XCD's 2 batches
    const int qi   = slot & 31;
    const int b    = xcd * 2 + half;
    const int qt   = half ? qi : (31 - qi);

    const int tid  = threadIdx.x;
    const int wave = tid >> 6;
    const int lane = tid & 63;
    const int lg   = lane >> 4;    // lane group 0..3
    const int lc   = lane & 15;

    __shared__ __align__(16) bf16_t K_lds[2][KB][KPAD];     // [buf][k][d]
    __shared__ __align__(16) bf16_t Vt_lds[2][D_H][KPAD];   // [buf][d][k]
    __shared__ __align__(16) bf16_t P_lds[4][16][KPAD];     // per-wave [q][k]

    const size_t bbase = (size_t)b * L_SEQ * D_H;

    // ---- Q fragments in registers, pre-scaled ----
    const int qrow = qt * QB + wave * 16 + lc;
    bf16x8 qa[2];
#pragma unroll
    for (int h = 0; h < 2; ++h) {
        const float* qp = Qg + bbase + (size_t)qrow * D_H + h * 32 + lg * 8;
        const f32x4 f0 = *reinterpret_cast<const f32x4*>(qp);
        const f32x4 f1 = *reinterpret_cast<const f32x4*>(qp + 4);
        bf16x8 a;
#pragma unroll
        for (int j = 0; j < 4; ++j) { a[j] = (bf16_t)(f0[j] * QSCALE); a[4 + j] = (bf16_t)(f1[j] * QSCALE); }
        qa[h] = a;
    }

    f32x4 o[4];
    float m[4], l[4];
#pragma unroll
    for (int r = 0; r < 4; ++r) { o[r] = (f32x4){0.f, 0.f, 0.f, 0.f}; m[r] = -1e30f; l[r] = 0.f; }

    const int qg0 = qt * QB + wave * 16 + lg * 4;   // global q row of acc reg 0

    // ---- staging: all 256 threads stage K (64x64) and V (transposed 4x4 blocks) ----
    auto stage = [&](int kt, int buf) {
        const int kbase = kt * KB;
#pragma unroll
        for (int i = 0; i < 4; ++i) {
            const int f  = i * 256 + tid;          // float4 index 0..1023
            const int r  = f >> 4;                 // k row 0..63
            const int c4 = (f & 15) * 4;           // d col
            const f32x4 kv = *reinterpret_cast<const f32x4*>(Kg + bbase + (size_t)(kbase + r) * D_H + c4);
            bf16x4 k4 = { (bf16_t)kv[0], (bf16_t)kv[1], (bf16_t)kv[2], (bf16_t)kv[3] };
            *reinterpret_cast<bf16x4*>(&K_lds[buf][r][c4]) = k4;
        }
        const int bi = tid >> 4;                   // k block 0..15
        const int bj = tid & 15;                   // d block 0..15
        f32x4 rows[4];
#pragma unroll
        for (int i = 0; i < 4; ++i)
            rows[i] = *reinterpret_cast<const f32x4*>(Vg + bbase + (size_t)(kbase + bi * 4 + i) * D_H + bj * 4);
#pragma unroll
        for (int j = 0; j < 4; ++j) {
            bf16x4 cj = { (bf16_t)rows[0][j], (bf16_t)rows[1][j], (bf16_t)rows[2][j], (bf16_t)rows[3][j] };
            *reinterpret_cast<bf16x4*>(&Vt_lds[buf][bj * 4 + j][bi * 4]) = cj;
        }
    };

    auto compute = [&](int kt, int buf, bool diag) {
        const int kbase = kt * KB;
        // ---- S = Q K^T (log2 units). Same (lane,j)->d map for both operands. ----
        f32x4 s[4];
#pragma unroll
        for (int n = 0; n < 4; ++n) {
            f32x4 acc = (f32x4){0.f, 0.f, 0.f, 0.f};
#pragma unroll
            for (int h = 0; h < 2; ++h) {
                const bf16x8 kb = *reinterpret_cast<const bf16x8*>(&K_lds[buf][n * 16 + lc][h * 32 + lg * 8]);
                acc = __builtin_amdgcn_mfma_f32_16x16x32_bf16(qa[h], kb, acc, 0, 0, 0);
            }
            s[n] = acc;
        }
        if (diag) {
#pragma unroll
            for (int n = 0; n < 4; ++n) {
                const int kg = kbase + n * 16 + lc;
#pragma unroll
                for (int r = 0; r < 4; ++r)
                    if (kg > qg0 + r) s[n][r] = -1e30f;
            }
        }
        // ---- online softmax (base-2); row r lives in the 16 lanes sharing lg ----
        float alpha[4];
#pragma unroll
        for (int r = 0; r < 4; ++r) {
            float mx = fmaxf(fmaxf(s[0][r], s[1][r]), fmaxf(s[2][r], s[3][r]));
            mx = fmaxf(mx, __shfl_xor(mx, 1));
            mx = fmaxf(mx, __shfl_xor(mx, 2));
            mx = fmaxf(mx, __shfl_xor(mx, 4));
            mx = fmaxf(mx, __shfl_xor(mx, 8));
            const float mn = fmaxf(m[r], mx);
            alpha[r] = exp2f(m[r] - mn);
            m[r] = mn;
            float rs = 0.f;
#pragma unroll
            for (int n = 0; n < 4; ++n) {
                // round P to bf16 NOW; l sums the rounded values so it matches PV exactly
                const bf16_t pb = (bf16_t)exp2f(s[n][r] - mn);
                P_lds[wave][lg * 4 + r][n * 16 + lc] = pb;
                rs += (float)pb;
            }
            rs += __shfl_xor(rs, 1);
            rs += __shfl_xor(rs, 2);
            rs += __shfl_xor(rs, 4);
            rs += __shfl_xor(rs, 8);
            l[r] = l[r] * alpha[r] + rs;
        }
#pragma unroll
        for (int dt = 0; dt < 4; ++dt)
#pragma unroll
            for (int r = 0; r < 4; ++r) o[dt][r] *= alpha[r];
        // ---- O += P V (per-wave P; in-wave LDS RAW ordered by compiler) ----
#pragma unroll
        for (int ks = 0; ks < 2; ++ks) {
            const bf16x8 pa = *reinterpret_cast<const bf16x8*>(&P_lds[wave][lc][ks * 32 + lg * 8]);
#pragma unroll
            for (int dt = 0; dt < 4; ++dt) {
                const bf16x8 vb = *reinterpret_cast<const bf16x8*>(&Vt_lds[buf][dt * 16 + lc][ks * 32 + lg * 8]);
                o[dt] = __builtin_amdgcn_mfma_f32_16x16x32_bf16(pa, vb, o[dt], 0, 0, 0);
            }
        }
    };

    // ---- main loop: double-buffered, one barrier per iteration ----
    stage(0, 0);
    __syncthreads();
    int cur = 0;
    for (int kt = 0; kt <= qt; ++kt) {
        if (kt < qt) stage(kt + 1, cur ^ 1);
        compute(kt, cur, kt == qt);
        __syncthreads();
        cur ^= 1;
    }

    // ---- epilogue: O / l ----
#pragma unroll
    for (int r = 0; r < 4; ++r) {
        const float inv = 1.0f / l[r];
        float* op = Og + bbase + (size_t)(qg0 + r) * D_H + lc;
#pragma unroll
        for (int dt = 0; dt < 4; ++dt) op[dt * 16] = o[dt][r] * inv;
    }
}

extern "C" void kernel_launch(void* const* d_in, const int* in_sizes, int n_in,
                              void* d_out, int out_size, void* d_ws, size_t ws_size,
                              hipStream_t stream)
{
    const float* Q = (const float*)d_in[0];
    const float* K = (const float*)d_in[1];
    const float* V = (const float*)d_in[2];
    float* O = (float*)d_out;
    attn_fwd_kernel<<<dim3(NQT * B_SZ), dim3(256), 0, stream>>>(Q, K, V, O);
}

// Round 3
// 45.895 us; speedup vs baseline: 2.9458x; 1.3595x over previous
//
#include <hip/hip_runtime.h>

typedef __bf16 bf16_t;
typedef __bf16 bf16x4 __attribute__((ext_vector_type(4)));
typedef __bf16 bf16x8 __attribute__((ext_vector_type(8)));
typedef float  f32x4  __attribute__((ext_vector_type(4)));

#define B_SZ  16
#define L_SEQ 2048
#define D_H   64
#define QB    64
#define KB    128
#define NQT   (L_SEQ / QB)   // 32

// softmax is over (S/8); fold log2(e)/8 into Q so MFMA output is in log2 units
#define QSCALE 0.18033688011112043f

__global__ __launch_bounds__(256, 2)
void attn_fwd_kernel(const float* __restrict__ Qg, const float* __restrict__ Kg,
                     const float* __restrict__ Vg, float* __restrict__ Og)
{
    // XCD-aware decode: 2 batches per XCD (K+V fp32 = 2 MB -> fits 4 MB L2),
    // balanced qt pairing: co-resident blocks lin, lin+256 get qt=31-qi and qt=qi.
    const int lin  = blockIdx.x;          // 0..511
    const int xcd  = lin & 7;
    const int slot = lin >> 3;            // 0..63
    const int half = slot >> 5;
    const int qi   = slot & 31;
    const int b    = xcd * 2 + half;
    const int qt   = half ? qi : (31 - qi);

    const int tid  = threadIdx.x;
    const int wave = tid >> 6;
    const int lane = tid & 63;
    const int lg   = lane >> 4;    // lane group 0..3
    const int lc   = lane & 15;

    __shared__ __align__(16) bf16_t K_lds[2][KB][72];      // [buf][k][d]   36.9 KB
    __shared__ __align__(16) bf16_t Vt_lds[2][D_H][136];   // [buf][d][k]   34.8 KB
    __shared__ __align__(16) bf16_t P_s[4][16][40];        // per-wave [q][k32]  5 KB

    const size_t bbase = (size_t)b * L_SEQ * D_H;

    // ---- Q fragment (B-operand of swapped QK: lane lc <-> q, (lg,j) <-> d) ----
    const int qrow = qt * QB + wave * 16 + lc;
    bf16x8 qa[2];
#pragma unroll
    for (int h = 0; h < 2; ++h) {
        const float* qp = Qg + bbase + (size_t)qrow * D_H + h * 32 + lg * 8;
        const f32x4 f0 = *reinterpret_cast<const f32x4*>(qp);
        const f32x4 f1 = *reinterpret_cast<const f32x4*>(qp + 4);
        bf16x8 a;
#pragma unroll
        for (int j = 0; j < 4; ++j) { a[j] = (bf16_t)(f0[j] * QSCALE); a[4 + j] = (bf16_t)(f1[j] * QSCALE); }
        qa[h] = a;
    }

    // O^T accumulator: o[dt][r] = O[d = dt*16 + lg*4 + r][q = qrow]
    f32x4 o[4];
#pragma unroll
    for (int dt = 0; dt < 4; ++dt) o[dt] = (f32x4){0.f, 0.f, 0.f, 0.f};
    float m = -1e30f, l = 0.f;

    const int nkt = (qt + 2) >> 1;        // number of 128-wide K tiles (last one masked)

    // ---- staging: 256 threads; K coalesced rows, V transposed 4x4 blocks ----
    const int vkb = tid & 31;             // k-block (4 rows) 0..31
    const int vdg = tid >> 5;             // 0..7 -> d-blocks vdg, vdg+8

    f32x4 kreg[8], vreg[8];

    auto issueK = [&](int kt) {
        const int kbase = kt * KB;
#pragma unroll
        for (int i = 0; i < 8; ++i) {
            const int f = i * 256 + tid;
            const int r = f >> 4, c4 = (f & 15) * 4;
            kreg[i] = *reinterpret_cast<const f32x4*>(Kg + bbase + (size_t)(kbase + r) * D_H + c4);
        }
    };
    auto issueV = [&](int kt) {
        const int kbase = kt * KB;
#pragma unroll
        for (int d2 = 0; d2 < 2; ++d2)
#pragma unroll
            for (int i = 0; i < 4; ++i)
                vreg[d2 * 4 + i] = *reinterpret_cast<const f32x4*>(
                    Vg + bbase + (size_t)(kbase + vkb * 4 + i) * D_H + (vdg + d2 * 8) * 4);
    };
    auto writeK = [&](int buf) {
#pragma unroll
        for (int i = 0; i < 8; ++i) {
            const int f = i * 256 + tid;
            const int r = f >> 4, c4 = (f & 15) * 4;
            bf16x4 k4 = { (bf16_t)kreg[i][0], (bf16_t)kreg[i][1], (bf16_t)kreg[i][2], (bf16_t)kreg[i][3] };
            *reinterpret_cast<bf16x4*>(&K_lds[buf][r][c4]) = k4;
        }
    };
    auto writeV = [&](int buf) {
#pragma unroll
        for (int d2 = 0; d2 < 2; ++d2) {
            const int db = vdg + d2 * 8;
#pragma unroll
            for (int j = 0; j < 4; ++j) {
                bf16x4 cj = { (bf16_t)vreg[d2 * 4 + 0][j], (bf16_t)vreg[d2 * 4 + 1][j],
                              (bf16_t)vreg[d2 * 4 + 2][j], (bf16_t)vreg[d2 * 4 + 3][j] };
                *reinterpret_cast<bf16x4*>(&Vt_lds[buf][db * 4 + j][vkb * 4]) = cj;
            }
        }
    };

    // ---- main loop: double-buffered, 1 barrier/iter, loads in flight across compute ----
    issueK(0); issueV(0); writeK(0); writeV(0);
    __syncthreads();
    int cur = 0;
    for (int kt = 0; kt < nkt; ++kt) {
        const bool last = (kt == nkt - 1);
        const int kbase = kt * KB;
        if (!last) issueK(kt + 1);

        // ---- S^T = K Q^T (log2 units): s[n][r] = S[k=kbase+n*16+lg*4+r][q=qrow] ----
        f32x4 s[8];
#pragma unroll
        for (int n = 0; n < 8; ++n) {
            f32x4 acc = (f32x4){0.f, 0.f, 0.f, 0.f};
#pragma unroll
            for (int h = 0; h < 2; ++h) {
                const bf16x8 kb = *reinterpret_cast<const bf16x8*>(&K_lds[cur][n * 16 + lc][h * 32 + lg * 8]);
                acc = __builtin_amdgcn_mfma_f32_16x16x32_bf16(kb, qa[h], acc, 0, 0, 0);
            }
            s[n] = acc;
        }
        if (!last) issueV(kt + 1);
        if (last) {
#pragma unroll
            for (int n = 0; n < 8; ++n)
#pragma unroll
                for (int r = 0; r < 4; ++r)
                    if (kbase + n * 16 + lg * 4 + r > qrow) s[n][r] = -1e30f;
        }

        // ---- per-lane online softmax for q = qrow ----
        float mx = -1e30f;
#pragma unroll
        for (int n = 0; n < 8; ++n)
            mx = fmaxf(mx, fmaxf(fmaxf(s[n][0], s[n][1]), fmaxf(s[n][2], s[n][3])));
        mx = fmaxf(mx, __shfl_xor(mx, 16));
        mx = fmaxf(mx, __shfl_xor(mx, 32));
        const float mn = fmaxf(m, mx);
        const float alpha = exp2f(m - mn);
        m = mn;
        bf16x4 u[8];
        float rs = 0.f;
#pragma unroll
        for (int n = 0; n < 8; ++n) {
            const float p0 = exp2f(s[n][0] - mn), p1 = exp2f(s[n][1] - mn);
            const float p2 = exp2f(s[n][2] - mn), p3 = exp2f(s[n][3] - mn);
            rs += (p0 + p1) + (p2 + p3);
            u[n] = (bf16x4){ (bf16_t)p0, (bf16_t)p1, (bf16_t)p2, (bf16_t)p3 };
        }
        rs += __shfl_xor(rs, 16);
        rs += __shfl_xor(rs, 32);
        l = l * alpha + rs;
#pragma unroll
        for (int dt = 0; dt < 4; ++dt)
#pragma unroll
            for (int r = 0; r < 4; ++r) o[dt][r] *= alpha;

        if (!last) writeK(cur ^ 1);   // free kreg before PV

        // ---- O^T += V^T P : stream P through per-wave LDS (32 k at a time) ----
#pragma unroll
        for (int ks = 0; ks < 4; ++ks) {
            *reinterpret_cast<bf16x4*>(&P_s[wave][lc][lg * 4])      = u[2 * ks];
            *reinterpret_cast<bf16x4*>(&P_s[wave][lc][16 + lg * 4]) = u[2 * ks + 1];
            const bf16x8 pb = *reinterpret_cast<const bf16x8*>(&P_s[wave][lc][lg * 8]);
#pragma unroll
            for (int dt = 0; dt < 4; ++dt) {
                const bf16x8 vb = *reinterpret_cast<const bf16x8*>(&Vt_lds[cur][dt * 16 + lc][ks * 32 + lg * 8]);
                o[dt] = __builtin_amdgcn_mfma_f32_16x16x32_bf16(vb, pb, o[dt], 0, 0, 0);
            }
        }

        if (!last) writeV(cur ^ 1);
        __syncthreads();
        cur ^= 1;
    }

    // ---- epilogue: O = O^T / l, vectorized stores ----
    const float inv = 1.0f / l;
#pragma unroll
    for (int dt = 0; dt < 4; ++dt) {
        f32x4 val = { o[dt][0] * inv, o[dt][1] * inv, o[dt][2] * inv, o[dt][3] * inv };
        *reinterpret_cast<f32x4*>(Og + bbase + (size_t)qrow * D_H + dt * 16 + lg * 4) = val;
    }
}

extern "C" void kernel_launch(void* const* d_in, const int* in_sizes, int n_in,
                              void* d_out, int out_size, void* d_ws, size_t ws_size,
                              hipStream_t stream)
{
    const float* Q = (const float*)d_in[0];
    const float* K = (const float*)d_in[1];
    const float* V = (const float*)d_in[2];
    float* O = (float*)d_out;
    attn_fwd_kernel<<<dim3(NQT * B_SZ), dim3(256), 0, stream>>>(Q, K, V, O);
}

// Round 4
// 39.697 us; speedup vs baseline: 3.4057x; 1.1561x over previous
//
#include <hip/hip_runtime.h>

typedef __bf16 bf16_t;
typedef __bf16 bf16x4 __attribute__((ext_vector_type(4)));
typedef __bf16 bf16x8 __attribute__((ext_vector_type(8)));
typedef float  f32x4  __attribute__((ext_vector_type(4)));

#define B_SZ  16
#define L_SEQ 2048
#define D_H   64
#define QB    64
#define KB    128
#define NQT   (L_SEQ / QB)   // 32

// softmax is over (S/8); fold log2(e)/8 into Q so MFMA output is in log2 units
#define QSCALE 0.18033688011112043f

__global__ __launch_bounds__(256, 2)
void attn_fwd_kernel(const float* __restrict__ Qg, const float* __restrict__ Kg,
                     const float* __restrict__ Vg, float* __restrict__ Og)
{
    // XCD-aware decode: 2 batches per XCD (K+V fp32 = 2 MB -> fits 4 MB L2),
    // balanced qt pairing: co-resident blocks get qt=31-qi and qt=qi (33 iters/CU).
    const int lin  = blockIdx.x;          // 0..511
    const int xcd  = lin & 7;
    const int slot = lin >> 3;            // 0..63
    const int half = slot >> 5;
    const int qi   = slot & 31;
    const int b    = xcd * 2 + half;
    const int qt   = half ? qi : (31 - qi);

    const int tid  = threadIdx.x;
    const int lane = tid & 63;
    const int lg   = lane >> 4;    // lane group 0..3
    const int lc   = lane & 15;

    __shared__ __align__(16) bf16_t K_lds[2][KB][72];      // [buf][k][d]   36.9 KB
    __shared__ __align__(16) bf16_t Vt_lds[2][D_H][136];   // [buf][d][pos] 34.8 KB (phi-permuted)

    const size_t bbase = (size_t)b * L_SEQ * D_H;

    // ---- Q fragment (B-operand of swapped QK: lane lc <-> q, (lg,j) <-> d) ----
    const int qrow = qt * QB + (tid >> 6) * 16 + lc;
    bf16x8 qa[2];
#pragma unroll
    for (int h = 0; h < 2; ++h) {
        const float* qp = Qg + bbase + (size_t)qrow * D_H + h * 32 + lg * 8;
        const f32x4 f0 = *reinterpret_cast<const f32x4*>(qp);
        const f32x4 f1 = *reinterpret_cast<const f32x4*>(qp + 4);
        bf16x8 a;
#pragma unroll
        for (int j = 0; j < 4; ++j) { a[j] = (bf16_t)(f0[j] * QSCALE); a[4 + j] = (bf16_t)(f1[j] * QSCALE); }
        qa[h] = a;
    }

    // O^T accumulator: o[dt][r] = O[d = dt*16 + lg*4 + r][q = qrow]
    f32x4 o[4];
#pragma unroll
    for (int dt = 0; dt < 4; ++dt) o[dt] = (f32x4){0.f, 0.f, 0.f, 0.f};
    float m = -1e30f, l = 0.f;

    const int nkt = (qt + 2) >> 1;        // number of 128-wide K tiles (last one masked)

    // ---- staging: 256 threads; K coalesced rows, V transposed + phi-permuted cols ----
    const int vkb = tid & 31;             // k-block (4 rows) 0..31
    const int vdg = tid >> 5;             // 0..7 -> d-blocks vdg, vdg+8
    // phi-permuted column base for this thread's 4 consecutive k values:
    const int vpos = ((vkb >> 3) << 5) + ((vkb & 3) << 3) + (((vkb >> 2) & 1) << 2);

    f32x4 kreg[8], vreg[8];

    auto issueK = [&](int kt) {
        const int kbase = kt * KB;
#pragma unroll
        for (int i = 0; i < 8; ++i) {
            const int f = i * 256 + tid;
            const int r = f >> 4, c4 = (f & 15) * 4;
            kreg[i] = *reinterpret_cast<const f32x4*>(Kg + bbase + (size_t)(kbase + r) * D_H + c4);
        }
    };
    auto issueV = [&](int kt) {
        const int kbase = kt * KB;
#pragma unroll
        for (int d2 = 0; d2 < 2; ++d2)
#pragma unroll
            for (int i = 0; i < 4; ++i)
                vreg[d2 * 4 + i] = *reinterpret_cast<const f32x4*>(
                    Vg + bbase + (size_t)(kbase + vkb * 4 + i) * D_H + (vdg + d2 * 8) * 4);
    };
    auto writeK = [&](int buf) {
#pragma unroll
        for (int i = 0; i < 8; ++i) {
            const int f = i * 256 + tid;
            const int r = f >> 4, c4 = (f & 15) * 4;
            bf16x4 k4 = { (bf16_t)kreg[i][0], (bf16_t)kreg[i][1], (bf16_t)kreg[i][2], (bf16_t)kreg[i][3] };
            *reinterpret_cast<bf16x4*>(&K_lds[buf][r][c4]) = k4;
        }
    };
    auto writeV = [&](int buf) {
#pragma unroll
        for (int d2 = 0; d2 < 2; ++d2) {
            const int db = vdg + d2 * 8;
#pragma unroll
            for (int j = 0; j < 4; ++j) {
                bf16x4 cj = { (bf16_t)vreg[d2 * 4 + 0][j], (bf16_t)vreg[d2 * 4 + 1][j],
                              (bf16_t)vreg[d2 * 4 + 2][j], (bf16_t)vreg[d2 * 4 + 3][j] };
                *reinterpret_cast<bf16x4*>(&Vt_lds[buf][db * 4 + j][vpos]) = cj;
            }
        }
    };

    // ---- main loop: double-buffered, 1 barrier/iter, loads in flight across compute ----
    issueK(0); issueV(0); writeK(0); writeV(0);
    __syncthreads();
    int cur = 0;
    for (int kt = 0; kt < nkt; ++kt) {
        const bool last = (kt == nkt - 1);
        const int kbase = kt * KB;
        if (!last) issueK(kt + 1);

        // ---- S^T = K Q^T (log2 units): s[n][r] = S[k=kbase+n*16+lg*4+r][q=qrow] ----
        f32x4 s[8];
        __builtin_amdgcn_s_setprio(1);
#pragma unroll
        for (int n = 0; n < 8; ++n) {
            f32x4 acc = (f32x4){0.f, 0.f, 0.f, 0.f};
#pragma unroll
            for (int h = 0; h < 2; ++h) {
                const bf16x8 kb = *reinterpret_cast<const bf16x8*>(&K_lds[cur][n * 16 + lc][h * 32 + lg * 8]);
                acc = __builtin_amdgcn_mfma_f32_16x16x32_bf16(kb, qa[h], acc, 0, 0, 0);
            }
            s[n] = acc;
        }
        __builtin_amdgcn_s_setprio(0);
        if (!last) issueV(kt + 1);
        if (last) {
#pragma unroll
            for (int n = 0; n < 8; ++n)
#pragma unroll
                for (int r = 0; r < 4; ++r)
                    if (kbase + n * 16 + lg * 4 + r > qrow) s[n][r] = -1e30f;
        }

        // ---- per-lane online softmax for q = qrow (max3-friendly tree) ----
        float mx = -1e30f;
#pragma unroll
        for (int n = 0; n < 8; ++n) {
            mx = fmaxf(fmaxf(mx, s[n][0]), fmaxf(s[n][1], fmaxf(s[n][2], s[n][3])));
        }
        mx = fmaxf(mx, __shfl_xor(mx, 16));
        mx = fmaxf(mx, __shfl_xor(mx, 32));
        const float mn = fmaxf(m, mx);
        const float alpha = exp2f(m - mn);
        m = mn;
        // P packed directly into the PV B-operand layout: w[ks] = (u[2ks], u[2ks+1]).
        // Slot map phi(lg,j) = (j>>2)*16 + lg*4 + (j&3); V^T is stored phi-permuted.
        bf16x8 w[4];
        float rs = 0.f;
#pragma unroll
        for (int n = 0; n < 8; ++n) {
            const float p0 = exp2f(s[n][0] - mn), p1 = exp2f(s[n][1] - mn);
            const float p2 = exp2f(s[n][2] - mn), p3 = exp2f(s[n][3] - mn);
            rs += (p0 + p1) + (p2 + p3);
            const int wi = n >> 1, off = (n & 1) * 4;
            w[wi][off + 0] = (bf16_t)p0; w[wi][off + 1] = (bf16_t)p1;
            w[wi][off + 2] = (bf16_t)p2; w[wi][off + 3] = (bf16_t)p3;
        }
        rs += __shfl_xor(rs, 16);
        rs += __shfl_xor(rs, 32);
        l = l * alpha + rs;
#pragma unroll
        for (int dt = 0; dt < 4; ++dt)
#pragma unroll
            for (int r = 0; r < 4; ++r) o[dt][r] *= alpha;

        if (!last) writeK(cur ^ 1);   // free kreg before PV

        // ---- O^T += V^T P : P straight from registers, Vtp from phi-permuted LDS ----
        __builtin_amdgcn_s_setprio(1);
#pragma unroll
        for (int ks = 0; ks < 4; ++ks) {
#pragma unroll
            for (int dt = 0; dt < 4; ++dt) {
                const bf16x8 vb = *reinterpret_cast<const bf16x8*>(&Vt_lds[cur][dt * 16 + lc][ks * 32 + lg * 8]);
                o[dt] = __builtin_amdgcn_mfma_f32_16x16x32_bf16(vb, w[ks], o[dt], 0, 0, 0);
            }
        }
        __builtin_amdgcn_s_setprio(0);

        if (!last) writeV(cur ^ 1);
        __syncthreads();
        cur ^= 1;
    }

    // ---- epilogue: O = O^T / l, vectorized stores ----
    const float inv = 1.0f / l;
#pragma unroll
    for (int dt = 0; dt < 4; ++dt) {
        f32x4 val = { o[dt][0] * inv, o[dt][1] * inv, o[dt][2] * inv, o[dt][3] * inv };
        *reinterpret_cast<f32x4*>(Og + bbase + (size_t)qrow * D_H + dt * 16 + lg * 4) = val;
    }
}

extern "C" void kernel_launch(void* const* d_in, const int* in_sizes, int n_in,
                              void* d_out, int out_size, void* d_ws, size_t ws_size,
                              hipStream_t stream)
{
    const float* Q = (const float*)d_in[0];
    const float* K = (const float*)d_in[1];
    const float* V = (const float*)d_in[2];
    float* O = (float*)d_out;
    attn_fwd_kernel<<<dim3(NQT * B_SZ), dim3(256), 0, stream>>>(Q, K, V, O);
}